// Round 10
// baseline (115.276 us; speedup 1.0000x reference)
//
#include <hip/hip_runtime.h>
#include <cstddef>

#define NN 4096   // nodes
#define NL 8      // layers
#define ND 128    // feature dim

#define CHUNK 128   // j's per block
#define BATCH 16    // GEMV slots per batch

typedef int   int4v   __attribute__((ext_vector_type(4)));
typedef float float4v __attribute__((ext_vector_type(4)));

// ---------------------------------------------------------------------------
// ONE kernel, 256 independent blocks = 32 chunks x 8 layers, 512 threads.
// Per block (owns 128 output rows of one layer):
//  1. src scan: descending rounds of 16 rows x 128 cols (int4); top rows are
//     shared by all 32 blocks of the layer -> L2/L3 hot. ~1-2 rounds expected.
//  2. deg row sums: its 128 chunk rows (exclusive 1/256 slice of the 512MB
//     stream; PLAIN loads so the 256MB L3 retains ~half of adj across graph
//     replays - round 8 measured FETCH 263MB for the full 512MB pass) + its
//     ~10 distinct src rows (L2/L3-hot).
//  3. GEMV Wf = W @ feature[src] for distinct srcs; W rows read from global
//     (L1-hot, reused across slots) - NOT cached in registers, keeping VGPR
//     <= 128 so 2+ blocks/CU stay resident for stream latency hiding.
//  4. scale + NT coalesced stores.
// ---------------------------------------------------------------------------
__global__ __launch_bounds__(512, 4) void fused_kernel(
    const float* __restrict__ feature, const float* __restrict__ W,
    const int* __restrict__ adj, float* __restrict__ out) {
  __shared__ int      s_cand[16][CHUNK];
  __shared__ int      s_src[CHUNK];
  __shared__ int      s_found[CHUNK];
  __shared__ unsigned s_mask[NN / 32];   // 128 words = 4096 bits
  __shared__ int      s_ps[NN / 32];
  __shared__ int      s_list[CHUNK];
  __shared__ int      s_smap[CHUNK];
  __shared__ float    s_scj[CHUNK];
  __shared__ float    s_deg[2 * CHUNK];
  __shared__ float    s_fb[BATCH][ND];
  __shared__ float    s_wf[BATCH][ND];

  const int t = threadIdx.x;
  const int l = blockIdx.y;
  const int jbase = blockIdx.x * CHUNK;
  const int* __restrict__ Al = adj + (size_t)l * NN * NN;

  // ---- phase 1: src scan (16 rows x 128 cols per round, early exit) ----
  if (t < CHUNK) { s_src[t] = jbase + t; s_found[t] = 0; }
  if (t < NN / 32) s_mask[t] = 0u;
  __syncthreads();

  const int rw = t >> 5;     // row offset 0..15
  const int cq = t & 31;     // int4 column within chunk
  int itop = NN - 1;
  for (;;) {
    const int i = itop - rw;
    int4v a = {0, 0, 0, 0};
    if (i > jbase)
      a = *reinterpret_cast<const int4v*>(Al + (size_t)i * NN + jbase + cq * 4);
    int4v c;
    c.x = (a.x != 0 && i > jbase + cq * 4 + 0) ? i : -1;
    c.y = (a.y != 0 && i > jbase + cq * 4 + 1) ? i : -1;
    c.z = (a.z != 0 && i > jbase + cq * 4 + 2) ? i : -1;
    c.w = (a.w != 0 && i > jbase + cq * 4 + 3) ? i : -1;
    *reinterpret_cast<int4v*>(&s_cand[rw][cq * 4]) = c;
    __syncthreads();
    bool mydone = true;
    if (t < CHUNK) {
      if (!s_found[t]) {
        int best = -1;
#pragma unroll
        for (int k = 0; k < 16; ++k) best = max(best, s_cand[k][t]);
        if (best >= 0) { s_src[t] = best; s_found[t] = 1; }
      }
      mydone = s_found[t] || (itop - 16 <= jbase + t);
    }
    itop -= 16;
    if (__syncthreads_and((int)mydone) || itop < 0) break;
  }

  // ---- phase 2: dedup distinct srcs (bitmask + prefix scan, ascending) ----
  if (t < CHUNK) atomicOr(&s_mask[s_src[t] >> 5], 1u << (s_src[t] & 31));
  __syncthreads();
  int pc = 0;
  if (t < 128) { pc = __popc(s_mask[t]); s_ps[t] = pc; }
  __syncthreads();
  for (int off = 1; off < 128; off <<= 1) {
    int v = 0;
    if (t < 128 && t >= off) v = s_ps[t - off];
    __syncthreads();
    if (t < 128 && t >= off) s_ps[t] += v;
    __syncthreads();
  }
  if (t < 128) {
    unsigned m = s_mask[t];
    int pos = s_ps[t] - pc;
    while (m) {
      int b = __ffs(m) - 1;
      m &= m - 1;
      s_list[pos++] = (t << 5) | b;
    }
  }
  __syncthreads();
  const int cnt = s_ps[127];
  if (t < CHUNK) {
    const int v = s_src[t], w = v >> 5;
    const int base = (w > 0) ? s_ps[w - 1] : 0;
    s_smap[t] = base + __popc(s_mask[w] & ((1u << (v & 31)) - 1));
  }

  // ---- phase 3: row sums. chunk rows (exclusive stream, plain loads) ----
  const int wv = t >> 6;     // wave 0..7
  const int lane = t & 63;
  for (int r = wv; r < CHUNK; r += 8) {
    const int4v* __restrict__ p =
        reinterpret_cast<const int4v*>(Al + (size_t)(jbase + r) * NN);
    int s = 0;
#pragma unroll
    for (int k = 0; k < 16; ++k) {
      int4v v = p[lane + k * 64];
      s += v.x + v.y + v.z + v.w;
    }
    for (int off = 32; off > 0; off >>= 1) s += __shfl_down(s, off, 64);
    if (lane == 0) s_deg[r] = (float)s + 1.0f;
  }
  // src rows (L2/L3-hot, shared across the layer's blocks)
  for (int r = wv; r < cnt; r += 8) {
    const int4v* __restrict__ p =
        reinterpret_cast<const int4v*>(Al + (size_t)s_list[r] * NN);
    int s = 0;
#pragma unroll
    for (int k = 0; k < 16; ++k) {
      int4v v = p[lane + k * 64];
      s += v.x + v.y + v.z + v.w;
    }
    for (int off = 32; off > 0; off >>= 1) s += __shfl_down(s, off, 64);
    if (lane == 0) s_deg[CHUNK + r] = (float)s + 1.0f;
  }
  __syncthreads();
  if (t < CHUNK)
    s_scj[t] = rsqrtf(s_deg[t] * s_deg[CHUNK + s_smap[t]]);

  // ---- phase 4: batched GEMV (W rows from global, L1-hot) + NT stores ----
  const int d = t & 127;
  const int quarter = t >> 7;    // 0..3, each computes 4 of 16 batch slots
  const float4v* __restrict__ Wd =
      reinterpret_cast<const float4v*>(W + (size_t)d * ND);

  for (int b0 = 0; b0 < cnt; b0 += BATCH) {
    const int nb = min(BATCH, cnt - b0);
    {
      const int k = t >> 5, q = t & 31;
      if (k < nb)
        reinterpret_cast<float4v*>(s_fb[k])[q] =
            reinterpret_cast<const float4v*>(
                feature + ((size_t)s_list[b0 + k] * NL + l) * ND)[q];
    }
    __syncthreads();

#pragma unroll
    for (int kk = 0; kk < 4; ++kk) {
      const int k = quarter * 4 + kk;
      if (k < nb) {
        float4v a4 = {0.f, 0.f, 0.f, 0.f};
#pragma unroll
        for (int q = 0; q < 32; ++q)
          a4 += Wd[q] * reinterpret_cast<const float4v*>(s_fb[k])[q];
        s_wf[k][d] = a4.x + a4.y + a4.z + a4.w;
      }
    }
    __syncthreads();

    for (int idx = t; idx < CHUNK * 32; idx += 512) {
      const int r = idx >> 5, q = idx & 31;
      const int sl = s_smap[r] - b0;
      if (sl >= 0 && sl < nb) {
        const float sc = s_scj[r];
        float4v v = reinterpret_cast<const float4v*>(s_wf[sl])[q];
        v.x *= sc; v.y *= sc; v.z *= sc; v.w *= sc;
        __builtin_nontemporal_store(
            v, reinterpret_cast<float4v*>(out) +
                   ((size_t)(jbase + r) * NL + l) * 32 + q);
      }
    }
    __syncthreads();
  }
}

// ---------------------------------------------------------------------------
extern "C" void kernel_launch(void* const* d_in, const int* in_sizes, int n_in,
                              void* d_out, int out_size, void* d_ws,
                              size_t ws_size, hipStream_t stream) {
  const float* feature = (const float*)d_in[0];   // [NN, NL, ND] f32
  const float* W       = (const float*)d_in[1];   // [ND, ND]     f32
  const int*   adj     = (const int*)d_in[2];     // [NL, NN, NN] i32
  float* out = (float*)d_out;                     // [NN, NL, ND] f32

  fused_kernel<<<dim3(NN / CHUNK, NL), 512, 0, stream>>>(feature, W, adj, out);
}

// Round 11
// 96.145 us; speedup vs baseline: 1.1990x; 1.1990x over previous
//
#include <hip/hip_runtime.h>
#include <cstddef>

#define NN 4096   // nodes
#define NL 8      // layers
#define ND 128    // feature dim

#define CHUNK 128   // j's per block
#define BATCH 16    // GEMV slots per batch

typedef int   int4v   __attribute__((ext_vector_type(4)));
typedef float float4v __attribute__((ext_vector_type(4)));

// ---------------------------------------------------------------------------
// Round-9 structure (known-good 97.4us), ONE change: the chunk-row stream
// splits by row parity -- even rows PLAIN (allocate -> L3 retains 256MB =
// exactly Infinity Cache capacity across graph replays), odd rows NT
// (stream from HBM, no allocation pressure on the retained half). The two
// supply paths (HBM ~256MB, L3 ~256MB) then serve the stream concurrently.
// ---------------------------------------------------------------------------
__global__ __launch_bounds__(512, 2) void fused_kernel(
    const float* __restrict__ feature, const float* __restrict__ W,
    const int* __restrict__ adj, float* __restrict__ out) {
  __shared__ int      s_cand[16][CHUNK];
  __shared__ int      s_src[CHUNK];
  __shared__ int      s_found[CHUNK];
  __shared__ unsigned s_mask[NN / 32];   // 128 words = 4096 bits
  __shared__ int      s_ps[NN / 32];
  __shared__ int      s_list[CHUNK];
  __shared__ int      s_smap[CHUNK];
  __shared__ float    s_scj[CHUNK];
  __shared__ float    s_deg[2 * CHUNK];
  __shared__ float    s_fb[BATCH][ND];
  __shared__ float    s_wf[BATCH][ND];

  const int t = threadIdx.x;
  const int l = blockIdx.y;
  const int jbase = blockIdx.x * CHUNK;
  const int* __restrict__ Al = adj + (size_t)l * NN * NN;

  // ---- phase 1: src scan (16 rows x 128 cols per round, early exit) ----
  if (t < CHUNK) { s_src[t] = jbase + t; s_found[t] = 0; }
  if (t < NN / 32) s_mask[t] = 0u;
  __syncthreads();

  const int rw = t >> 5;     // row offset 0..15
  const int cq = t & 31;     // int4 column within chunk
  int itop = NN - 1;
  for (;;) {
    const int i = itop - rw;
    int4v a = {0, 0, 0, 0};
    if (i > jbase)
      a = *reinterpret_cast<const int4v*>(Al + (size_t)i * NN + jbase + cq * 4);
    int4v c;
    c.x = (a.x != 0 && i > jbase + cq * 4 + 0) ? i : -1;
    c.y = (a.y != 0 && i > jbase + cq * 4 + 1) ? i : -1;
    c.z = (a.z != 0 && i > jbase + cq * 4 + 2) ? i : -1;
    c.w = (a.w != 0 && i > jbase + cq * 4 + 3) ? i : -1;
    *reinterpret_cast<int4v*>(&s_cand[rw][cq * 4]) = c;
    __syncthreads();
    bool mydone = true;
    if (t < CHUNK) {
      if (!s_found[t]) {
        int best = -1;
#pragma unroll
        for (int k = 0; k < 16; ++k) best = max(best, s_cand[k][t]);
        if (best >= 0) { s_src[t] = best; s_found[t] = 1; }
      }
      mydone = s_found[t] || (itop - 16 <= jbase + t);
    }
    itop -= 16;
    if (__syncthreads_and((int)mydone) || itop < 0) break;
  }

  // ---- phase 2: dedup distinct srcs (bitmask + prefix scan, ascending) ----
  if (t < CHUNK) atomicOr(&s_mask[s_src[t] >> 5], 1u << (s_src[t] & 31));
  __syncthreads();
  int pc = 0;
  if (t < 128) { pc = __popc(s_mask[t]); s_ps[t] = pc; }
  __syncthreads();
  for (int off = 1; off < 128; off <<= 1) {
    int v = 0;
    if (t < 128 && t >= off) v = s_ps[t - off];
    __syncthreads();
    if (t < 128 && t >= off) s_ps[t] += v;
    __syncthreads();
  }
  if (t < 128) {
    unsigned m = s_mask[t];
    int pos = s_ps[t] - pc;
    while (m) {
      int b = __ffs(m) - 1;
      m &= m - 1;
      s_list[pos++] = (t << 5) | b;
    }
  }
  __syncthreads();
  const int cnt = s_ps[127];
  if (t < CHUNK) {
    const int v = s_src[t], w = v >> 5;
    const int base = (w > 0) ? s_ps[w - 1] : 0;
    s_smap[t] = base + __popc(s_mask[w] & ((1u << (v & 31)) - 1));
  }

  // ---- phase 3: row sums. chunk rows: even rows PLAIN (L3-retained),
  //      odd rows NT (HBM stream) ----
  const int wv = t >> 6;     // wave 0..7
  const int lane = t & 63;
  for (int r = wv; r < CHUNK; r += 8) {
    const int row = jbase + r;
    const int4v* __restrict__ p =
        reinterpret_cast<const int4v*>(Al + (size_t)row * NN);
    int s = 0;
    if (row & 1) {
#pragma unroll
      for (int k = 0; k < 16; ++k) {
        int4v v = __builtin_nontemporal_load(&p[lane + k * 64]);
        s += v.x + v.y + v.z + v.w;
      }
    } else {
#pragma unroll
      for (int k = 0; k < 16; ++k) {
        int4v v = p[lane + k * 64];
        s += v.x + v.y + v.z + v.w;
      }
    }
    for (int off = 32; off > 0; off >>= 1) s += __shfl_down(s, off, 64);
    if (lane == 0) s_deg[r] = (float)s + 1.0f;
  }
  // src rows (L2/L3-hot, shared across the layer's blocks)
  for (int r = wv; r < cnt; r += 8) {
    const int4v* __restrict__ p =
        reinterpret_cast<const int4v*>(Al + (size_t)s_list[r] * NN);
    int s = 0;
#pragma unroll
    for (int k = 0; k < 16; ++k) {
      int4v v = p[lane + k * 64];
      s += v.x + v.y + v.z + v.w;
    }
    for (int off = 32; off > 0; off >>= 1) s += __shfl_down(s, off, 64);
    if (lane == 0) s_deg[CHUNK + r] = (float)s + 1.0f;
  }
  __syncthreads();
  if (t < CHUNK)
    s_scj[t] = rsqrtf(s_deg[t] * s_deg[CHUNK + s_smap[t]]);

  // ---- phase 4: W rows into registers, batched GEMV + scaled NT stores ----
  const int d = t & 127;
  const int quarter = t >> 7;    // 0..3, each computes 4 of 16 batch slots
  float4v wreg[32];
#pragma unroll
  for (int q = 0; q < 32; ++q)
    wreg[q] = reinterpret_cast<const float4v*>(W)[d * 32 + q];

  for (int b0 = 0; b0 < cnt; b0 += BATCH) {
    const int nb = min(BATCH, cnt - b0);
    {
      const int k = t >> 5, q = t & 31;
      if (k < nb)
        reinterpret_cast<float4v*>(s_fb[k])[q] =
            reinterpret_cast<const float4v*>(
                feature + ((size_t)s_list[b0 + k] * NL + l) * ND)[q];
    }
    __syncthreads();

#pragma unroll
    for (int kk = 0; kk < 4; ++kk) {
      const int k = quarter * 4 + kk;
      if (k < nb) {
        float4v a4 = {0.f, 0.f, 0.f, 0.f};
#pragma unroll
        for (int q = 0; q < 32; ++q)
          a4 += wreg[q] * reinterpret_cast<const float4v*>(s_fb[k])[q];
        s_wf[k][d] = a4.x + a4.y + a4.z + a4.w;
      }
    }
    __syncthreads();

    for (int idx = t; idx < CHUNK * 32; idx += 512) {
      const int r = idx >> 5, q = idx & 31;
      const int sl = s_smap[r] - b0;
      if (sl >= 0 && sl < nb) {
        const float sc = s_scj[r];
        float4v v = reinterpret_cast<const float4v*>(s_wf[sl])[q];
        v.x *= sc; v.y *= sc; v.z *= sc; v.w *= sc;
        __builtin_nontemporal_store(
            v, reinterpret_cast<float4v*>(out) +
                   ((size_t)(jbase + r) * NL + l) * 32 + q);
      }
    }
    __syncthreads();
  }
}

// ---------------------------------------------------------------------------
extern "C" void kernel_launch(void* const* d_in, const int* in_sizes, int n_in,
                              void* d_out, int out_size, void* d_ws,
                              size_t ws_size, hipStream_t stream) {
  const float* feature = (const float*)d_in[0];   // [NN, NL, ND] f32
  const float* W       = (const float*)d_in[1];   // [ND, ND]     f32
  const int*   adj     = (const int*)d_in[2];     // [NL, NN, NN] i32
  float* out = (float*)d_out;                     // [NN, NL, ND] f32

  fused_kernel<<<dim3(NN / CHUNK, NL), 512, 0, stream>>>(feature, W, adj, out);
}